// Round 5
// baseline (584.060 us; speedup 1.0000x reference)
//
#include <hip/hip_runtime.h>
#include <hip/hip_bf16.h>
#include <stdint.h>
#include <string.h>

#define NN 50000
#define NE 800000

typedef short bf8_t __attribute__((ext_vector_type(8)));
typedef float f32x4 __attribute__((ext_vector_type(4)));

// silu via native exp + v_rcp (saves ~9 VALU ops vs IEEE div; ~1ulp rcp fine for bf16)
__device__ __forceinline__ float silu_f(float v) {
    return v * __builtin_amdgcn_rcpf(1.0f + __expf(-v));
}

__device__ __forceinline__ unsigned int pack2bf(float a, float b) {
    __hip_bfloat162 h = __float22bfloat162_rn(make_float2(a, b));   // v_cvt_pk_bf16_f32
    unsigned int u; memcpy(&u, &h, 4);
    return u;
}

union U4B { uint4 u; bf8_t b; };
__device__ __forceinline__ bf8_t as_bf8(uint4 u) { U4B x; x.u = u; return x.b; }

__device__ __forceinline__ void nt_store_u64(void* p, uint2 v) {
    unsigned long long u = (unsigned long long)v.x | ((unsigned long long)v.y << 32);
    __builtin_nontemporal_store(u, (unsigned long long*)p);
}

// ---------------------------------------------------------------------------
// prep: x f32 -> bf16, fused with edge-row histogram (both index spaces = 800k)
// ---------------------------------------------------------------------------
__global__ __launch_bounds__(256) void prep_x_hist(const float* __restrict__ x,
                                                   unsigned short* __restrict__ xbf,
                                                   const int* __restrict__ ei,
                                                   int* __restrict__ cnt) {
    size_t i = (size_t)blockIdx.x * 256 + threadIdx.x;
    const float4* s = (const float4*)(x + i * 8);
    float4 v0 = s[0], v1 = s[1];
    uint4 o;
    o.x = pack2bf(v0.x, v0.y); o.y = pack2bf(v0.z, v0.w);
    o.z = pack2bf(v1.x, v1.y); o.w = pack2bf(v1.z, v1.w);
    *(uint4*)(xbf + i * 8) = o;
    atomicAdd(&cnt[ei[i]], 1);
}

// ---------------------------------------------------------------------------
// prep: weight fragments in MFMA A-operand order (W^T), bf16.
// frag f = s*8 + mf: lane holds W[k = s*32 + (lane>>4)*8 + i][col = mf*16 + (lane&15)]
// ---------------------------------------------------------------------------
__global__ __launch_bounds__(64) void prep_w(const float* __restrict__ We1,
                                             const float* __restrict__ We2,
                                             const float* __restrict__ Wn1,
                                             const float* __restrict__ Wn2,
                                             unsigned short* __restrict__ wf1,
                                             unsigned short* __restrict__ wf2,
                                             unsigned short* __restrict__ wfn1,
                                             unsigned short* __restrict__ wfn2) {
    int b = blockIdx.x, lane = threadIdx.x;
    int q = lane >> 4, c = lane & 15;
    const float* W; unsigned short* dst; int f;
    if (b < 64)       { W = We1; f = b;       dst = wf1  + (size_t)f * 512; }
    else if (b < 96)  { W = We2; f = b - 64;  dst = wf2  + (size_t)f * 512; }
    else if (b < 160) { W = Wn1; f = b - 96;  dst = wfn1 + (size_t)f * 512; }
    else              { W = Wn2; f = b - 160; dst = wfn2 + (size_t)f * 512; }
    int s = f >> 3, mf = f & 7;
    int k0 = s * 32 + q * 8, col = mf * 16 + c;
    float v[8];
    #pragma unroll
    for (int i = 0; i < 8; ++i) v[i] = W[(size_t)(k0 + i) * 128 + col];
    uint4 o;
    o.x = pack2bf(v[0], v[1]); o.y = pack2bf(v[2], v[3]);
    o.z = pack2bf(v[4], v[5]); o.w = pack2bf(v[6], v[7]);
    *(uint4*)(dst + lane * 8) = o;
}

// ---------------------------------------------------------------------------
// CSR build
// ---------------------------------------------------------------------------
__global__ __launch_bounds__(1024) void egnn_scan(const int* __restrict__ cnt,
                                                  int* __restrict__ off,
                                                  int* __restrict__ cur) {
    __shared__ int part[1024];
    const int t = threadIdx.x;
    const int CH = (NN + 1023) / 1024;
    int lo = t * CH, hi = lo + CH; if (hi > NN) hi = NN; if (lo > NN) lo = NN;
    int s = 0;
    for (int i = lo; i < hi; ++i) s += cnt[i];
    part[t] = s;
    __syncthreads();
    for (int d = 1; d < 1024; d <<= 1) {
        int v = (t >= d) ? part[t - d] : 0;
        __syncthreads();
        part[t] += v;
        __syncthreads();
    }
    int base = (t == 0) ? 0 : part[t - 1];
    for (int i = lo; i < hi; ++i) { off[i] = base; cur[i] = base; base += cnt[i]; }
    if (t == 1023) off[NN] = NE;
}

__global__ __launch_bounds__(256) void egnn_scatter(const int* __restrict__ ei,
                                                    int* __restrict__ cur,
                                                    int* __restrict__ elist) {
    int e = blockIdx.x * 256 + threadIdx.x;
    if (e < NE) { int p = atomicAdd(&cur[ei[e]], 1); elist[p] = e; }
}

// ---------------------------------------------------------------------------
// Edge MFMA kernel, CSR-slot order. Block = 128 slots, 512 threads, 8 waves.
// Weights from global frag buffers (L2-resident). m/trans nt-stored at slot
// index (sequential; nontemporal keeps xbf L2/L3-resident).
// ---------------------------------------------------------------------------
__global__ __launch_bounds__(512, 4) void egnn_edge_mfma(
    const unsigned short* __restrict__ xbf, const float* __restrict__ pos,
    const unsigned short* __restrict__ wf1, const unsigned short* __restrict__ wf2,
    const float* __restrict__ We1, const float* __restrict__ be1,
    const float* __restrict__ be2, const float* __restrict__ Wc,
    const float* __restrict__ bc,
    const int* __restrict__ ei, const int* __restrict__ elist,
    unsigned short* __restrict__ m_out, float* __restrict__ trans)
{
    __shared__ unsigned short Hs[128 * 136];   // 34.8 KB
    __shared__ int rows_s[128], cols_s[128];
    __shared__ float rij_s[128][3];
    __shared__ float dij_s[128];
    __shared__ float wdot[128];

    const int tid = threadIdx.x;
    const int e0 = blockIdx.x * 128;

    if (tid < 128) {
        int eid = elist[e0 + tid];
        int r = ei[eid], c = ei[NE + eid];
        rows_s[tid] = r; cols_s[tid] = c;
        float d = 0.f;
        #pragma unroll
        for (int k = 0; k < 3; ++k) {
            float rv = pos[r * 3 + k] - pos[c * 3 + k];
            rij_s[tid][k] = rv; d += rv * rv;
        }
        dij_s[tid] = d;
        wdot[tid] = 0.f;
    }
    __syncthreads();

    const int w = tid >> 6, lane = tid & 63;
    const int P = w & 3, Q = w >> 2;
    const int q = lane >> 4, e16 = lane & 15;
    const int oc_q = P * 32 + q * 4;

    int ridx[4], cidx[4], eloc[4];
    #pragma unroll
    for (int t = 0; t < 4; ++t) {
        int el = Q * 64 + t * 16 + e16; eloc[t] = el;
        ridx[t] = rows_s[el]; cidx[t] = cols_s[el];
    }

    // ---- layer 1: K=256 MFMA; dij rank-1 + bias as f32 fixup ----
    f32x4 acc[2][4];
    #pragma unroll
    for (int M = 0; M < 2; ++M) {
        float4 bi = *(const float4*)(be1 + oc_q + M * 16);
        #pragma unroll
        for (int t = 0; t < 4; ++t) { acc[M][t][0] = bi.x; acc[M][t][1] = bi.y; acc[M][t][2] = bi.z; acc[M][t][3] = bi.w; }
    }

    #pragma unroll
    for (int s = 0; s < 8; ++s) {
        bf8_t bfr[4];
        #pragma unroll
        for (int t = 0; t < 4; ++t) {
            int node = (s < 4) ? ridx[t] : cidx[t];
            bfr[t] = as_bf8(*(const uint4*)(xbf + (size_t)node * 128 + (s & 3) * 32 + q * 8));
        }
        #pragma unroll
        for (int M = 0; M < 2; ++M) {
            bf8_t af = as_bf8(*(const uint4*)(wf1 + (size_t)(s * 8 + P * 2 + M) * 512 + lane * 8));
            #pragma unroll
            for (int t = 0; t < 4; ++t)
                acc[M][t] = __builtin_amdgcn_mfma_f32_16x16x32_bf16(af, bfr[t], acc[M][t], 0, 0, 0);
        }
    }

    #pragma unroll
    for (int M = 0; M < 2; ++M) {
        float4 w256 = *(const float4*)(We1 + (size_t)256 * 128 + oc_q + M * 16);
        #pragma unroll
        for (int t = 0; t < 4; ++t) {
            float d = dij_s[eloc[t]];
            float v0 = silu_f(acc[M][t][0] + d * w256.x);
            float v1 = silu_f(acc[M][t][1] + d * w256.y);
            float v2 = silu_f(acc[M][t][2] + d * w256.z);
            float v3 = silu_f(acc[M][t][3] + d * w256.w);
            uint2 pk; pk.x = pack2bf(v0, v1); pk.y = pack2bf(v2, v3);
            *(uint2*)(Hs + (size_t)eloc[t] * 136 + oc_q + M * 16) = pk;
        }
    }
    __syncthreads();

    // ---- layer 2: K=128 ----
    f32x4 acc2[2][4];
    #pragma unroll
    for (int M = 0; M < 2; ++M) {
        float4 bi = *(const float4*)(be2 + oc_q + M * 16);
        #pragma unroll
        for (int t = 0; t < 4; ++t) { acc2[M][t][0] = bi.x; acc2[M][t][1] = bi.y; acc2[M][t][2] = bi.z; acc2[M][t][3] = bi.w; }
    }

    #pragma unroll
    for (int s = 0; s < 4; ++s) {
        bf8_t bfr[4];
        #pragma unroll
        for (int t = 0; t < 4; ++t)
            bfr[t] = as_bf8(*(const uint4*)(Hs + (size_t)eloc[t] * 136 + s * 32 + q * 8));
        #pragma unroll
        for (int M = 0; M < 2; ++M) {
            bf8_t af = as_bf8(*(const uint4*)(wf2 + (size_t)(s * 8 + P * 2 + M) * 512 + lane * 8));
            #pragma unroll
            for (int t = 0; t < 4; ++t)
                acc2[M][t] = __builtin_amdgcn_mfma_f32_16x16x32_bf16(af, bfr[t], acc2[M][t], 0, 0, 0);
        }
    }

    // ---- epilogue: m = silu(.), nt-store at slot; wdot partials ----
    float4 wcA = *(const float4*)(Wc + oc_q);
    float4 wcB = *(const float4*)(Wc + oc_q + 16);
    float part[4];
    #pragma unroll
    for (int t = 0; t < 4; ++t) part[t] = 0.f;

    #pragma unroll
    for (int M = 0; M < 2; ++M) {
        float4 wc = (M == 0) ? wcA : wcB;
        #pragma unroll
        for (int t = 0; t < 4; ++t) {
            float v0 = silu_f(acc2[M][t][0]);
            float v1 = silu_f(acc2[M][t][1]);
            float v2 = silu_f(acc2[M][t][2]);
            float v3 = silu_f(acc2[M][t][3]);
            part[t] += v0 * wc.x + v1 * wc.y + v2 * wc.z + v3 * wc.w;
            uint2 pk; pk.x = pack2bf(v0, v1); pk.y = pack2bf(v2, v3);
            nt_store_u64(m_out + (size_t)(e0 + eloc[t]) * 128 + oc_q + M * 16, pk);
        }
    }
    #pragma unroll
    for (int t = 0; t < 4; ++t) {
        float p = part[t];
        p += __shfl_xor(p, 16);
        p += __shfl_xor(p, 32);
        if (q == 0) atomicAdd(&wdot[eloc[t]], p);
    }
    __syncthreads();

    if (tid < 128) {
        float wgt = silu_f(wdot[tid] + bc[0]);
        size_t slot = (size_t)(e0 + tid);
        __builtin_nontemporal_store(rij_s[tid][0] * wgt, trans + slot * 3 + 0);
        __builtin_nontemporal_store(rij_s[tid][1] * wgt, trans + slot * 3 + 1);
        __builtin_nontemporal_store(rij_s[tid][2] * wgt, trans + slot * 3 + 2);
    }
}

// ---------------------------------------------------------------------------
// Gather: one wave per node; m/trans CSR-ordered -> pure streaming (nt loads).
// Writes agg bf16 and pos_new directly into out.
// ---------------------------------------------------------------------------
__global__ __launch_bounds__(256) void egnn_gather(
    const unsigned short* __restrict__ m, const float* __restrict__ trans,
    const int* __restrict__ off, const float* __restrict__ pos,
    unsigned short* __restrict__ aggbf, float* __restrict__ out)
{
    int n = (blockIdx.x * 256 + threadIdx.x) >> 6;
    int lane = threadIdx.x & 63;
    const unsigned int* m32 = (const unsigned int*)m;
    int s = off[n], e_end = off[n + 1];
    float a0 = 0.f, a1 = 0.f, td = 0.f;
    for (int i = s; i < e_end; ++i) {
        unsigned int u = __builtin_nontemporal_load(m32 + (size_t)i * 64 + lane);
        a0 += __uint_as_float(u << 16);
        a1 += __uint_as_float(u & 0xffff0000u);
        if (lane < 3) td += __builtin_nontemporal_load(trans + (size_t)i * 3 + lane);
    }
    *(unsigned int*)(aggbf + (size_t)n * 128 + lane * 2) = pack2bf(a0, a1);
    if (lane < 3)
        out[(size_t)NN * 128 + (size_t)n * 3 + lane] =
            pos[(size_t)n * 3 + lane] + 0.01f * td;
}

// ---------------------------------------------------------------------------
// Node MFMA kernel: x_new = silu([x|agg] @ Wn1 + bn1) @ Wn2 + bn2
// ---------------------------------------------------------------------------
__global__ __launch_bounds__(512, 4) void egnn_node_mfma(
    const unsigned short* __restrict__ xbf, const unsigned short* __restrict__ aggbf,
    const unsigned short* __restrict__ wfn1, const unsigned short* __restrict__ wfn2,
    const float* __restrict__ bn1, const float* __restrict__ bn2,
    float* __restrict__ out)
{
    __shared__ unsigned short Hs[128 * 136];

    const int tid = threadIdx.x;
    const int n0 = blockIdx.x * 128;
    const int w = tid >> 6, lane = tid & 63;
    const int P = w & 3, Q = w >> 2;
    const int q = lane >> 4, e16 = lane & 15;
    const int oc_q = P * 32 + q * 4;

    int nloc[4], nclamp[4];
    #pragma unroll
    for (int t = 0; t < 4; ++t) {
        int nl = Q * 64 + t * 16 + e16; nloc[t] = nl;
        int node = n0 + nl; nclamp[t] = (node >= NN) ? NN - 1 : node;
    }

    f32x4 acc[2][4];
    #pragma unroll
    for (int M = 0; M < 2; ++M) {
        float4 bi = *(const float4*)(bn1 + oc_q + M * 16);
        #pragma unroll
        for (int t = 0; t < 4; ++t) { acc[M][t][0] = bi.x; acc[M][t][1] = bi.y; acc[M][t][2] = bi.z; acc[M][t][3] = bi.w; }
    }

    #pragma unroll
    for (int s = 0; s < 8; ++s) {
        bf8_t bfr[4];
        #pragma unroll
        for (int t = 0; t < 4; ++t) {
            const unsigned short* base = (s < 4) ? xbf : aggbf;
            bfr[t] = as_bf8(*(const uint4*)(base + (size_t)nclamp[t] * 128 + (s & 3) * 32 + q * 8));
        }
        #pragma unroll
        for (int M = 0; M < 2; ++M) {
            bf8_t af = as_bf8(*(const uint4*)(wfn1 + (size_t)(s * 8 + P * 2 + M) * 512 + lane * 8));
            #pragma unroll
            for (int t = 0; t < 4; ++t)
                acc[M][t] = __builtin_amdgcn_mfma_f32_16x16x32_bf16(af, bfr[t], acc[M][t], 0, 0, 0);
        }
    }

    #pragma unroll
    for (int M = 0; M < 2; ++M) {
        #pragma unroll
        for (int t = 0; t < 4; ++t) {
            float v0 = silu_f(acc[M][t][0]);
            float v1 = silu_f(acc[M][t][1]);
            float v2 = silu_f(acc[M][t][2]);
            float v3 = silu_f(acc[M][t][3]);
            uint2 pk; pk.x = pack2bf(v0, v1); pk.y = pack2bf(v2, v3);
            *(uint2*)(Hs + (size_t)nloc[t] * 136 + oc_q + M * 16) = pk;
        }
    }
    __syncthreads();

    f32x4 acc2[2][4];
    #pragma unroll
    for (int M = 0; M < 2; ++M) {
        float4 bi = *(const float4*)(bn2 + oc_q + M * 16);
        #pragma unroll
        for (int t = 0; t < 4; ++t) { acc2[M][t][0] = bi.x; acc2[M][t][1] = bi.y; acc2[M][t][2] = bi.z; acc2[M][t][3] = bi.w; }
    }

    #pragma unroll
    for (int s = 0; s < 4; ++s) {
        bf8_t bfr[4];
        #pragma unroll
        for (int t = 0; t < 4; ++t)
            bfr[t] = as_bf8(*(const uint4*)(Hs + (size_t)nloc[t] * 136 + s * 32 + q * 8));
        #pragma unroll
        for (int M = 0; M < 2; ++M) {
            bf8_t af = as_bf8(*(const uint4*)(wfn2 + (size_t)(s * 8 + P * 2 + M) * 512 + lane * 8));
            #pragma unroll
            for (int t = 0; t < 4; ++t)
                acc2[M][t] = __builtin_amdgcn_mfma_f32_16x16x32_bf16(af, bfr[t], acc2[M][t], 0, 0, 0);
        }
    }

    #pragma unroll
    for (int M = 0; M < 2; ++M) {
        #pragma unroll
        for (int t = 0; t < 4; ++t) {
            int node = n0 + nloc[t];
            if (node < NN) {
                float4 v; v.x = acc2[M][t][0]; v.y = acc2[M][t][1]; v.z = acc2[M][t][2]; v.w = acc2[M][t][3];
                *(float4*)(out + (size_t)node * 128 + oc_q + M * 16) = v;
            }
        }
    }
}

extern "C" void kernel_launch(void* const* d_in, const int* in_sizes, int n_in,
                              void* d_out, int out_size, void* d_ws, size_t ws_size,
                              hipStream_t stream)
{
    const float* x   = (const float*)d_in[0];
    const float* pos = (const float*)d_in[1];
    const float* We1 = (const float*)d_in[2];
    const float* be1 = (const float*)d_in[3];
    const float* We2 = (const float*)d_in[4];
    const float* be2 = (const float*)d_in[5];
    const float* Wn1 = (const float*)d_in[6];
    const float* bn1 = (const float*)d_in[7];
    const float* Wn2 = (const float*)d_in[8];
    const float* bn2 = (const float*)d_in[9];
    const float* Wc  = (const float*)d_in[10];
    const float* bc  = (const float*)d_in[11];
    const int*   ei  = (const int*)d_in[12];
    float* out = (float*)d_out;

    char* p = (char*)d_ws;
    unsigned short* m = (unsigned short*)p;    p += (size_t)NE * 128 * 2;   // 204.8 MB (CSR-slot order)
    float* trans = (float*)p;                  p += (size_t)NE * 3 * 4;     //   9.6 MB
    unsigned short* xbf = (unsigned short*)p;  p += (size_t)NN * 128 * 2;   //  12.8 MB
    unsigned short* aggbf = (unsigned short*)p; p += (size_t)NN * 128 * 2;  //  12.8 MB
    unsigned short* wf1  = (unsigned short*)p; p += 65536;
    unsigned short* wf2  = (unsigned short*)p; p += 32768;
    unsigned short* wfn1 = (unsigned short*)p; p += 65536;
    unsigned short* wfn2 = (unsigned short*)p; p += 32768;
    int* cnt   = (int*)p;                      p += (size_t)NN * 4;
    int* off   = (int*)p;                      p += (size_t)(NN + 1) * 4 + 12;
    int* cur   = (int*)p;                      p += (size_t)NN * 4;
    int* elist = (int*)p;

    hipMemsetAsync(cnt, 0, (size_t)NN * 4, stream);
    prep_x_hist<<<3125, 256, 0, stream>>>(x, xbf, ei, cnt);
    prep_w<<<192, 64, 0, stream>>>(We1, We2, Wn1, Wn2, wf1, wf2, wfn1, wfn2);
    egnn_scan<<<1, 1024, 0, stream>>>(cnt, off, cur);
    egnn_scatter<<<NE / 256, 256, 0, stream>>>(ei, cur, elist);
    egnn_edge_mfma<<<NE / 128, 512, 0, stream>>>(xbf, pos, wf1, wf2, We1, be1, be2,
                                                 Wc, bc, ei, elist, m, trans);
    egnn_gather<<<(NN * 64) / 256, 256, 0, stream>>>(m, trans, off, pos, aggbf, out);
    egnn_node_mfma<<<(NN + 127) / 128, 512, 0, stream>>>(xbf, aggbf, wfn1, wfn2, bn1, bn2, out);
}

// Round 6
// 458.604 us; speedup vs baseline: 1.2736x; 1.2736x over previous
//
#include <hip/hip_runtime.h>
#include <hip/hip_bf16.h>
#include <stdint.h>
#include <string.h>

#define NN 50000
#define NE 800000

typedef short bf8_t __attribute__((ext_vector_type(8)));
typedef float f32x4 __attribute__((ext_vector_type(4)));

// silu via native exp + v_rcp
__device__ __forceinline__ float silu_f(float v) {
    return v * __builtin_amdgcn_rcpf(1.0f + __expf(-v));
}

__device__ __forceinline__ unsigned int pack2bf(float a, float b) {
    __hip_bfloat162 h = __float22bfloat162_rn(make_float2(a, b));   // v_cvt_pk_bf16_f32
    unsigned int u; memcpy(&u, &h, 4);
    return u;
}

__device__ __forceinline__ float bf_lo(unsigned int u) { return __uint_as_float(u << 16); }
__device__ __forceinline__ float bf_hi(unsigned int u) { return __uint_as_float(u & 0xffff0000u); }

union U4B { uint4 u; bf8_t b; };
__device__ __forceinline__ bf8_t as_bf8(uint4 u) { U4B x; x.u = u; return x.b; }

// k-th set bit of the 128-bit mask (m0 = slots 0..63, m1 = 64..127)
__device__ __forceinline__ int kth_bit(unsigned long long m0, unsigned long long m1, int k) {
    int c0 = __popcll(m0);
    unsigned long long m; int base;
    if (k < c0) { m = m0; base = 0; }
    else        { m = m1; base = 64; k -= c0; }
    for (int i = 0; i < k; ++i) m &= m - 1;
    return base + __ffsll((long long)m) - 1;
}

// ---------------------------------------------------------------------------
// prep: x f32 -> bf16, fused with edge-row histogram (both index spaces 800k)
// ---------------------------------------------------------------------------
__global__ __launch_bounds__(256) void prep_x_hist(const float* __restrict__ x,
                                                   unsigned short* __restrict__ xbf,
                                                   const int* __restrict__ ei,
                                                   int* __restrict__ cnt) {
    size_t i = (size_t)blockIdx.x * 256 + threadIdx.x;
    const float4* s = (const float4*)(x + i * 8);
    float4 v0 = s[0], v1 = s[1];
    uint4 o;
    o.x = pack2bf(v0.x, v0.y); o.y = pack2bf(v0.z, v0.w);
    o.z = pack2bf(v1.x, v1.y); o.w = pack2bf(v1.z, v1.w);
    *(uint4*)(xbf + i * 8) = o;
    atomicAdd(&cnt[ei[i]], 1);
}

// ---------------------------------------------------------------------------
// prep: weight fragments in MFMA A-operand order (W^T), bf16.
// ---------------------------------------------------------------------------
__global__ __launch_bounds__(64) void prep_w(const float* __restrict__ We1,
                                             const float* __restrict__ We2,
                                             const float* __restrict__ Wn1,
                                             const float* __restrict__ Wn2,
                                             unsigned short* __restrict__ wf1,
                                             unsigned short* __restrict__ wf2,
                                             unsigned short* __restrict__ wfn1,
                                             unsigned short* __restrict__ wfn2) {
    int b = blockIdx.x, lane = threadIdx.x;
    int q = lane >> 4, c = lane & 15;
    const float* W; unsigned short* dst; int f;
    if (b < 64)       { W = We1; f = b;       dst = wf1  + (size_t)f * 512; }
    else if (b < 96)  { W = We2; f = b - 64;  dst = wf2  + (size_t)f * 512; }
    else if (b < 160) { W = Wn1; f = b - 96;  dst = wfn1 + (size_t)f * 512; }
    else              { W = Wn2; f = b - 160; dst = wfn2 + (size_t)f * 512; }
    int s = f >> 3, mf = f & 7;
    int k0 = s * 32 + q * 8, col = mf * 16 + c;
    float v[8];
    #pragma unroll
    for (int i = 0; i < 8; ++i) v[i] = W[(size_t)(k0 + i) * 128 + col];
    uint4 o;
    o.x = pack2bf(v[0], v[1]); o.y = pack2bf(v[2], v[3]);
    o.z = pack2bf(v[4], v[5]); o.w = pack2bf(v[6], v[7]);
    *(uint4*)(dst + lane * 8) = o;
}

// ---------------------------------------------------------------------------
// CSR build
// ---------------------------------------------------------------------------
__global__ __launch_bounds__(1024) void egnn_scan(const int* __restrict__ cnt,
                                                  int* __restrict__ off,
                                                  int* __restrict__ cur) {
    __shared__ int part[1024];
    const int t = threadIdx.x;
    const int CH = (NN + 1023) / 1024;
    int lo = t * CH, hi = lo + CH; if (hi > NN) hi = NN; if (lo > NN) lo = NN;
    int s = 0;
    for (int i = lo; i < hi; ++i) s += cnt[i];
    part[t] = s;
    __syncthreads();
    for (int d = 1; d < 1024; d <<= 1) {
        int v = (t >= d) ? part[t - d] : 0;
        __syncthreads();
        part[t] += v;
        __syncthreads();
    }
    int base = (t == 0) ? 0 : part[t - 1];
    for (int i = lo; i < hi; ++i) { off[i] = base; cur[i] = base; base += cnt[i]; }
    if (t == 1023) off[NN] = NE;
}

// scatter: materialize row/col ids in CSR slot order (no elist indirection later)
__global__ __launch_bounds__(256) void egnn_scatter(const int* __restrict__ ei,
                                                    int* __restrict__ cur,
                                                    int* __restrict__ row_slot,
                                                    int* __restrict__ col_slot) {
    int e = blockIdx.x * 256 + threadIdx.x;
    if (e < NE) {
        int r = ei[e];
        int p = atomicAdd(&cur[r], 1);
        row_slot[p] = r;
        col_slot[p] = ei[NE + e];
    }
}

// ---------------------------------------------------------------------------
// Edge MFMA kernel with FUSED aggregation. Block = 128 CSR slots, 512 thr.
// After the two MLP layers, m is staged in LDS (bf16), per-node segments are
// detected via ballot on sorted row_slot, summed in-block, and written to
// f32 agg/delta: direct stores for interior segments, atomics only for the
// (<=2) block-boundary segments. No m/trans global round-trip.
// ---------------------------------------------------------------------------
__global__ __launch_bounds__(512, 4) void egnn_edge_mfma(
    const unsigned short* __restrict__ xbf, const float* __restrict__ pos,
    const unsigned short* __restrict__ wf1, const unsigned short* __restrict__ wf2,
    const float* __restrict__ We1, const float* __restrict__ be1,
    const float* __restrict__ be2, const float* __restrict__ Wc,
    const float* __restrict__ bc,
    const int* __restrict__ row_slot, const int* __restrict__ col_slot,
    float* __restrict__ agg, float* __restrict__ delta)
{
    __shared__ __align__(16) char HsBuf[128 * 136 * 2];   // h1 tile, later m tile
    unsigned short* Hs = (unsigned short*)HsBuf;           // stride 136 (u16)
    unsigned int*  mls = (unsigned int*)HsBuf;             // stride 66  (u32)
    __shared__ int   rows_s[128], cols_s[128];
    __shared__ float rij_s[128][3];                        // becomes trans in place
    __shared__ float dij_s[128];
    __shared__ float wdot[128];
    __shared__ unsigned long long smask[2];
    __shared__ int firstPartial, lastPartial;

    const int tid = threadIdx.x;
    const int e0 = blockIdx.x * 128;

    if (tid < 128) {
        int r = row_slot[e0 + tid], c = col_slot[e0 + tid];
        rows_s[tid] = r; cols_s[tid] = c;
        float d = 0.f;
        #pragma unroll
        for (int k = 0; k < 3; ++k) {
            float rv = pos[r * 3 + k] - pos[c * 3 + k];
            rij_s[tid][k] = rv; d += rv * rv;
        }
        dij_s[tid] = d;
        wdot[tid] = 0.f;
    }
    __syncthreads();

    const int w = tid >> 6, lane = tid & 63;
    const int P = w & 3, Q = w >> 2;
    const int q = lane >> 4, e16 = lane & 15;
    const int oc_q = P * 32 + q * 4;

    int ridx[4], cidx[4], eloc[4];
    #pragma unroll
    for (int t = 0; t < 4; ++t) {
        int el = Q * 64 + t * 16 + e16; eloc[t] = el;
        ridx[t] = rows_s[el]; cidx[t] = cols_s[el];
    }

    // ---- layer 1: K=256 MFMA; dij rank-1 + bias as f32 fixup ----
    f32x4 acc[2][4];
    #pragma unroll
    for (int M = 0; M < 2; ++M) {
        float4 bi = *(const float4*)(be1 + oc_q + M * 16);
        #pragma unroll
        for (int t = 0; t < 4; ++t) { acc[M][t][0] = bi.x; acc[M][t][1] = bi.y; acc[M][t][2] = bi.z; acc[M][t][3] = bi.w; }
    }

    #pragma unroll
    for (int s = 0; s < 8; ++s) {
        bf8_t bfr[4];
        #pragma unroll
        for (int t = 0; t < 4; ++t) {
            int node = (s < 4) ? ridx[t] : cidx[t];
            bfr[t] = as_bf8(*(const uint4*)(xbf + (size_t)node * 128 + (s & 3) * 32 + q * 8));
        }
        #pragma unroll
        for (int M = 0; M < 2; ++M) {
            bf8_t af = as_bf8(*(const uint4*)(wf1 + (size_t)(s * 8 + P * 2 + M) * 512 + lane * 8));
            #pragma unroll
            for (int t = 0; t < 4; ++t)
                acc[M][t] = __builtin_amdgcn_mfma_f32_16x16x32_bf16(af, bfr[t], acc[M][t], 0, 0, 0);
        }
    }

    #pragma unroll
    for (int M = 0; M < 2; ++M) {
        float4 w256 = *(const float4*)(We1 + (size_t)256 * 128 + oc_q + M * 16);
        #pragma unroll
        for (int t = 0; t < 4; ++t) {
            float d = dij_s[eloc[t]];
            float v0 = silu_f(acc[M][t][0] + d * w256.x);
            float v1 = silu_f(acc[M][t][1] + d * w256.y);
            float v2 = silu_f(acc[M][t][2] + d * w256.z);
            float v3 = silu_f(acc[M][t][3] + d * w256.w);
            uint2 pk; pk.x = pack2bf(v0, v1); pk.y = pack2bf(v2, v3);
            *(uint2*)(Hs + (size_t)eloc[t] * 136 + oc_q + M * 16) = pk;
        }
    }
    __syncthreads();

    // ---- layer 2: K=128 ----
    f32x4 acc2[2][4];
    #pragma unroll
    for (int M = 0; M < 2; ++M) {
        float4 bi = *(const float4*)(be2 + oc_q + M * 16);
        #pragma unroll
        for (int t = 0; t < 4; ++t) { acc2[M][t][0] = bi.x; acc2[M][t][1] = bi.y; acc2[M][t][2] = bi.z; acc2[M][t][3] = bi.w; }
    }

    #pragma unroll
    for (int s = 0; s < 4; ++s) {
        bf8_t bfr[4];
        #pragma unroll
        for (int t = 0; t < 4; ++t)
            bfr[t] = as_bf8(*(const uint4*)(Hs + (size_t)eloc[t] * 136 + s * 32 + q * 8));
        #pragma unroll
        for (int M = 0; M < 2; ++M) {
            bf8_t af = as_bf8(*(const uint4*)(wf2 + (size_t)(s * 8 + P * 2 + M) * 512 + lane * 8));
            #pragma unroll
            for (int t = 0; t < 4; ++t)
                acc2[M][t] = __builtin_amdgcn_mfma_f32_16x16x32_bf16(af, bfr[t], acc2[M][t], 0, 0, 0);
        }
    }
    __syncthreads();   // all Hs reads done before m overwrites the buffer

    // ---- epilogue: m = silu(.) -> LDS (mls); per-slot Wc dot partials ----
    float4 wcA = *(const float4*)(Wc + oc_q);
    float4 wcB = *(const float4*)(Wc + oc_q + 16);
    float part[4];
    #pragma unroll
    for (int t = 0; t < 4; ++t) part[t] = 0.f;

    #pragma unroll
    for (int M = 0; M < 2; ++M) {
        float4 wc = (M == 0) ? wcA : wcB;
        #pragma unroll
        for (int t = 0; t < 4; ++t) {
            float v0 = silu_f(acc2[M][t][0]);
            float v1 = silu_f(acc2[M][t][1]);
            float v2 = silu_f(acc2[M][t][2]);
            float v3 = silu_f(acc2[M][t][3]);
            part[t] += v0 * wc.x + v1 * wc.y + v2 * wc.z + v3 * wc.w;
            // u32 col-pair index: cols (oc_q + M*16)/2 = P*16 + M*8 + q*2
            mls[(size_t)eloc[t] * 66 + P * 16 + M * 8 + q * 2]     = pack2bf(v0, v1);
            mls[(size_t)eloc[t] * 66 + P * 16 + M * 8 + q * 2 + 1] = pack2bf(v2, v3);
        }
    }
    #pragma unroll
    for (int t = 0; t < 4; ++t) {
        float p = part[t];
        p += __shfl_xor(p, 16);
        p += __shfl_xor(p, 32);
        if (q == 0) atomicAdd(&wdot[eloc[t]], p);
    }
    __syncthreads();   // mls + wdot complete

    // ---- per-slot trans (in place) + segment boundary detection ----
    if (tid < 128) {
        float wgt = silu_f(wdot[tid] + bc[0]);
        rij_s[tid][0] *= wgt; rij_s[tid][1] *= wgt; rij_s[tid][2] *= wgt;
        bool flag = (tid == 0) || (rows_s[tid] != rows_s[tid - 1]);
        unsigned long long b = __ballot(flag);
        if (lane == 0) smask[w] = b;   // w = 0 for tid<64, 1 for 64..127
        if (tid == 0) {
            firstPartial = (e0 > 0) && (row_slot[e0 - 1] == rows_s[0]);
            lastPartial  = (e0 + 128 < NE) && (row_slot[e0 + 128] == rows_s[127]);
        }
    }
    __syncthreads();

    // ---- segmented reduction: 8 groups x 64 col-pairs ----
    {
        const int c2 = tid & 63;          // u32 col pair -> cols 2c2, 2c2+1
        const int g  = tid >> 6;          // segment round-robin group
        unsigned long long m0 = smask[0], m1 = smask[1];
        int nseg = __popcll(m0) + __popcll(m1);
        for (int k = g; k < nseg; k += 8) {
            int start = kth_bit(m0, m1, k);
            int end   = (k + 1 < nseg) ? kth_bit(m0, m1, k + 1) : 128;
            int node  = rows_s[start];
            float a0 = 0.f, a1 = 0.f;
            for (int s2 = start; s2 < end; ++s2) {
                unsigned int u = mls[(size_t)s2 * 66 + c2];
                a0 += bf_lo(u); a1 += bf_hi(u);
            }
            bool partial = (k == 0 && firstPartial) || (k == nseg - 1 && lastPartial);
            float* dst = agg + (size_t)node * 128 + c2 * 2;
            if (partial) { atomicAdd(dst, a0); atomicAdd(dst + 1, a1); }
            else         { *(float2*)dst = make_float2(a0, a1); }
            if (c2 == 0) {
                float d0 = 0.f, d1 = 0.f, d2 = 0.f;
                for (int s2 = start; s2 < end; ++s2) {
                    d0 += rij_s[s2][0]; d1 += rij_s[s2][1]; d2 += rij_s[s2][2];
                }
                float* dd = delta + (size_t)node * 3;
                if (partial) { atomicAdd(dd, d0); atomicAdd(dd + 1, d1); atomicAdd(dd + 2, d2); }
                else         { dd[0] = d0; dd[1] = d1; dd[2] = d2; }
            }
        }
    }
}

// ---------------------------------------------------------------------------
// agg f32 -> bf16 + pos_new
// ---------------------------------------------------------------------------
__global__ __launch_bounds__(256) void prep_agg_pos(
    const float* __restrict__ agg, const float* __restrict__ delta,
    const float* __restrict__ pos, unsigned short* __restrict__ aggbf,
    float* __restrict__ out)
{
    int n = (blockIdx.x * 256 + threadIdx.x) >> 6;
    int lane = threadIdx.x & 63;
    if (n >= NN) return;
    float2 v = *(const float2*)(agg + (size_t)n * 128 + lane * 2);
    *(unsigned int*)(aggbf + (size_t)n * 128 + lane * 2) = pack2bf(v.x, v.y);
    if (lane < 3)
        out[(size_t)NN * 128 + (size_t)n * 3 + lane] =
            pos[(size_t)n * 3 + lane] + 0.01f * delta[(size_t)n * 3 + lane];
}

// ---------------------------------------------------------------------------
// Node MFMA kernel: x_new = silu([x|agg] @ Wn1 + bn1) @ Wn2 + bn2
// ---------------------------------------------------------------------------
__global__ __launch_bounds__(512, 4) void egnn_node_mfma(
    const unsigned short* __restrict__ xbf, const unsigned short* __restrict__ aggbf,
    const unsigned short* __restrict__ wfn1, const unsigned short* __restrict__ wfn2,
    const float* __restrict__ bn1, const float* __restrict__ bn2,
    float* __restrict__ out)
{
    __shared__ unsigned short Hs[128 * 136];

    const int tid = threadIdx.x;
    const int n0 = blockIdx.x * 128;
    const int w = tid >> 6, lane = tid & 63;
    const int P = w & 3, Q = w >> 2;
    const int q = lane >> 4, e16 = lane & 15;
    const int oc_q = P * 32 + q * 4;

    int nloc[4], nclamp[4];
    #pragma unroll
    for (int t = 0; t < 4; ++t) {
        int nl = Q * 64 + t * 16 + e16; nloc[t] = nl;
        int node = n0 + nl; nclamp[t] = (node >= NN) ? NN - 1 : node;
    }

    f32x4 acc[2][4];
    #pragma unroll
    for (int M = 0; M < 2; ++M) {
        float4 bi = *(const float4*)(bn1 + oc_q + M * 16);
        #pragma unroll
        for (int t = 0; t < 4; ++t) { acc[M][t][0] = bi.x; acc[M][t][1] = bi.y; acc[M][t][2] = bi.z; acc[M][t][3] = bi.w; }
    }

    #pragma unroll
    for (int s = 0; s < 8; ++s) {
        bf8_t bfr[4];
        #pragma unroll
        for (int t = 0; t < 4; ++t) {
            const unsigned short* base = (s < 4) ? xbf : aggbf;
            bfr[t] = as_bf8(*(const uint4*)(base + (size_t)nclamp[t] * 128 + (s & 3) * 32 + q * 8));
        }
        #pragma unroll
        for (int M = 0; M < 2; ++M) {
            bf8_t af = as_bf8(*(const uint4*)(wfn1 + (size_t)(s * 8 + P * 2 + M) * 512 + lane * 8));
            #pragma unroll
            for (int t = 0; t < 4; ++t)
                acc[M][t] = __builtin_amdgcn_mfma_f32_16x16x32_bf16(af, bfr[t], acc[M][t], 0, 0, 0);
        }
    }

    #pragma unroll
    for (int M = 0; M < 2; ++M) {
        #pragma unroll
        for (int t = 0; t < 4; ++t) {
            float v0 = silu_f(acc[M][t][0]);
            float v1 = silu_f(acc[M][t][1]);
            float v2 = silu_f(acc[M][t][2]);
            float v3 = silu_f(acc[M][t][3]);
            uint2 pk; pk.x = pack2bf(v0, v1); pk.y = pack2bf(v2, v3);
            *(uint2*)(Hs + (size_t)nloc[t] * 136 + oc_q + M * 16) = pk;
        }
    }
    __syncthreads();

    f32x4 acc2[2][4];
    #pragma unroll
    for (int M = 0; M < 2; ++M) {
        float4 bi = *(const float4*)(bn2 + oc_q + M * 16);
        #pragma unroll
        for (int t = 0; t < 4; ++t) { acc2[M][t][0] = bi.x; acc2[M][t][1] = bi.y; acc2[M][t][2] = bi.z; acc2[M][t][3] = bi.w; }
    }

    #pragma unroll
    for (int s = 0; s < 4; ++s) {
        bf8_t bfr[4];
        #pragma unroll
        for (int t = 0; t < 4; ++t)
            bfr[t] = as_bf8(*(const uint4*)(Hs + (size_t)nloc[t] * 136 + s * 32 + q * 8));
        #pragma unroll
        for (int M = 0; M < 2; ++M) {
            bf8_t af = as_bf8(*(const uint4*)(wfn2 + (size_t)(s * 8 + P * 2 + M) * 512 + lane * 8));
            #pragma unroll
            for (int t = 0; t < 4; ++t)
                acc2[M][t] = __builtin_amdgcn_mfma_f32_16x16x32_bf16(af, bfr[t], acc2[M][t], 0, 0, 0);
        }
    }

    #pragma unroll
    for (int M = 0; M < 2; ++M) {
        #pragma unroll
        for (int t = 0; t < 4; ++t) {
            int node = n0 + nloc[t];
            if (node < NN) {
                float4 v; v.x = acc2[M][t][0]; v.y = acc2[M][t][1]; v.z = acc2[M][t][2]; v.w = acc2[M][t][3];
                *(float4*)(out + (size_t)node * 128 + oc_q + M * 16) = v;
            }
        }
    }
}

extern "C" void kernel_launch(void* const* d_in, const int* in_sizes, int n_in,
                              void* d_out, int out_size, void* d_ws, size_t ws_size,
                              hipStream_t stream)
{
    const float* x   = (const float*)d_in[0];
    const float* pos = (const float*)d_in[1];
    const float* We1 = (const float*)d_in[2];
    const float* be1 = (const float*)d_in[3];
    const float* We2 = (const float*)d_in[4];
    const float* be2 = (const float*)d_in[5];
    const float* Wn1 = (const float*)d_in[6];
    const float* bn1 = (const float*)d_in[7];
    const float* Wn2 = (const float*)d_in[8];
    const float* bn2 = (const float*)d_in[9];
    const float* Wc  = (const float*)d_in[10];
    const float* bc  = (const float*)d_in[11];
    const int*   ei  = (const int*)d_in[12];
    float* out = (float*)d_out;

    char* p = (char*)d_ws;
    float* agg   = (float*)p;                  p += (size_t)NN * 128 * 4;   // 25.6 MB
    float* delta = (float*)p;                  p += (size_t)NN * 3 * 4;     // 0.6 MB (contiguous after agg)
    unsigned short* xbf = (unsigned short*)p;  p += (size_t)NN * 128 * 2;   // 12.8 MB
    unsigned short* aggbf = (unsigned short*)p; p += (size_t)NN * 128 * 2;  // 12.8 MB
    unsigned short* wf1  = (unsigned short*)p; p += 65536;
    unsigned short* wf2  = (unsigned short*)p; p += 32768;
    unsigned short* wfn1 = (unsigned short*)p; p += 65536;
    unsigned short* wfn2 = (unsigned short*)p; p += 32768;
    int* cnt   = (int*)p;                      p += (size_t)NN * 4;
    int* off   = (int*)p;                      p += (size_t)(NN + 1) * 4 + 12;
    int* cur   = (int*)p;                      p += (size_t)NN * 4;
    int* row_slot = (int*)p;                   p += (size_t)NE * 4;
    int* col_slot = (int*)p;

    // zero cnt + agg + delta (agg/delta contiguous)
    hipMemsetAsync(cnt, 0, (size_t)NN * 4, stream);
    hipMemsetAsync(agg, 0, ((size_t)NN * 128 + (size_t)NN * 3) * 4, stream);

    prep_x_hist<<<3125, 256, 0, stream>>>(x, xbf, ei, cnt);
    prep_w<<<192, 64, 0, stream>>>(We1, We2, Wn1, Wn2, wf1, wf2, wfn1, wfn2);
    egnn_scan<<<1, 1024, 0, stream>>>(cnt, off, cur);
    egnn_scatter<<<NE / 256, 256, 0, stream>>>(ei, cur, row_slot, col_slot);
    egnn_edge_mfma<<<NE / 128, 512, 0, stream>>>(xbf, pos, wf1, wf2, We1, be1, be2,
                                                 Wc, bc, row_slot, col_slot, agg, delta);
    prep_agg_pos<<<(NN * 64 + 255) / 256, 256, 0, stream>>>(agg, delta, pos, aggbf, out);
    egnn_node_mfma<<<(NN + 127) / 128, 512, 0, stream>>>(xbf, aggbf, wfn1, wfn2, bn1, bn2, out);
}